// Round 8
// baseline (9539.532 us; speedup 1.0000x reference)
//
#include <hip/hip_runtime.h>
#include <hip/hip_bf16.h>
#include <float.h>
#include <math.h>

#define NB 4
#define NN 8192
#define FF 64
#define MM 2048
#define KK 32
#define HH 64

#define FB 4            // fps blocks per cloud
#define FPB 2048        // points per fps block
#define FTH 512         // fps threads per block
#define LPT 4           // points per thread

typedef unsigned long long u64;

// 64-bit packed argmax DPP step: integer max on ((v_bits<<32)|((8191-oi)<<16))
// == max v, tie -> lower oi (v >= 0 so float bit order == value order).
// identity old = 0 (never wins meaningfully).
#define DPP64_STEP(b, ctrl, rmask)                                              \
    {                                                                           \
        const unsigned int _lo = (unsigned int)(b);                             \
        const unsigned int _hi = (unsigned int)((b) >> 32);                     \
        const unsigned int _olo = (unsigned int)__builtin_amdgcn_update_dpp(    \
            0, (int)_lo, (ctrl), (rmask), 0xf, false);                          \
        const unsigned int _ohi = (unsigned int)__builtin_amdgcn_update_dpp(    \
            0, (int)_hi, (ctrl), (rmask), 0xf, false);                          \
        const u64 _o = (((u64)_ohi) << 32) | _olo;                              \
        if (_o > (b)) (b) = _o;                                                 \
    }
#define DPP64_REDUCE(b)            \
    DPP64_STEP(b, 0x111, 0xf)      \
    DPP64_STEP(b, 0x112, 0xf)      \
    DPP64_STEP(b, 0x114, 0xf)      \
    DPP64_STEP(b, 0x118, 0xf)      \
    DPP64_STEP(b, 0x142, 0xa)      \
    DPP64_STEP(b, 0x143, 0xc)

// ---------------- init: zero the cross-block sync words (replay-safe) ----------
__global__ void zero_sync_kernel(u64* __restrict__ syncW) {
    if (threadIdx.x < NB * FB * 2) syncW[threadIdx.x] = 0ull;
}

// ------------- Kernel 1: exact FPS, 4 blocks per cloud, L3 handshake -----------
__global__ __launch_bounds__(FTH) void fps_kernel(
    const float* __restrict__ pos,
    u64* __restrict__ syncW,
    int* __restrict__ samp,
    float* __restrict__ centers_out,
    float* __restrict__ batch_out)
{
    __shared__ float4 pts4[FPB];          // this block's 2048 points (32 KB)
    __shared__ u64 wslot[2][8];           // parity-buffered per-wave winners

    const int cloud = blockIdx.x >> 2;
    const int me    = blockIdx.x & 3;
    const float* pb = pos + (size_t)cloud * NN * 3;
    const int base  = me * FPB;           // cloud-local index of our first point
    const int tid = threadIdx.x;
    const int w   = tid >> 6;
    const int lane = tid & 63;
    u64* W = syncW + cloud * (FB * 2);    // [block][parity]

    // ---- stage our slice; prefill batch ids ----
    for (int j = tid; j < FPB; j += FTH) {
        const int g = base + j;
        pts4[j] = make_float4(pb[g * 3 + 0], pb[g * 3 + 1], pb[g * 3 + 2], 0.0f);
    }
    if (me == 0)
        for (int j = tid; j < MM; j += FTH) batch_out[cloud * MM + j] = (float)cloud;

    float dist[LPT];
#pragma unroll
    for (int i = 0; i < LPT; ++i) dist[i] = INFINITY;
    __syncthreads();

    int   cur = 0;
    float lx = pb[0], ly = pb[1], lz = pb[2];

    for (int s = 0; s < MM; ++s) {
        if (me == 0 && tid == 0) {
            samp[cloud * MM + s] = cur;
            centers_out[((size_t)cloud * MM + s) * 3 + 0] = lx;
            centers_out[((size_t)cloud * MM + s) * 3 + 1] = ly;
            centers_out[((size_t)cloud * MM + s) * 3 + 2] = lz;
        }
        if (s == MM - 1) break;   // last argmax unused by the reference

        const int par = s & 1;

        // ---- local update over our 2048 points (pure reg/LDS, exact math) ----
        u64 best = 0ull;
#pragma unroll
        for (int i = 0; i < LPT; ++i) {
            const int sl = i * FTH + tid;
            const float4 p = pts4[sl];
            // exact ref arithmetic: ((dx*dx + dy*dy) + dz*dz), no FMA contraction
            const float dx = __fsub_rn(p.x, lx);
            const float dy = __fsub_rn(p.y, ly);
            const float dz = __fsub_rn(p.z, lz);
            const float d  = __fadd_rn(__fadd_rn(__fmul_rn(dx, dx),
                                                 __fmul_rn(dy, dy)),
                                       __fmul_rn(dz, dz));
            const float nd = fminf(dist[i], d);
            dist[i] = nd;
            const u64 pk = (((u64)(unsigned int)__float_as_int(nd)) << 32)
                         | (((u64)(8191 - (base + sl))) << 16);
            if (pk > best) best = pk;
        }

        // ---- wave reduce (u64 DPP max), block reduce via 8 LDS slots ----
        DPP64_REDUCE(best)
        if (lane == 63) wslot[par][w] = best;
        __syncthreads();

        u64 bb = wslot[par][0];
#pragma unroll
        for (int k = 1; k < 8; ++k) {
            const u64 v = wslot[par][k];
            if (v > bb) bb = v;
        }
        bb |= (u64)(s + 1);   // tag in low 16 bits (packing left them zero)

        // ---- publish our block winner (device-scope RMW -> coherence point) ----
        if (tid == 0) atomicExch(&W[me * 2 + par], bb);

        // ---- spin on the 3 peers (device-scope acquire loads) ----
        u64 fin = bb;
#pragma unroll
        for (int p = 0; p < FB; ++p) {
            if (p == me) continue;
            u64 v;
            do {
                v = __hip_atomic_load(&W[p * 2 + par], __ATOMIC_ACQUIRE,
                                      __HIP_MEMORY_SCOPE_AGENT);
            } while ((v & 0xFFFFull) != (u64)(s + 1));
            if (v > fin) fin = v;
        }

        cur = 8191 - (int)((fin >> 16) & 0xFFFFull);
        lx = pb[cur * 3 + 0];     // read-only global: bitwise == ref coords
        ly = pb[cur * 3 + 1];
        lz = pb[cur * 3 + 2];
    }
}

// ---------------- Kernel 2: radius-KNN, one wave per center ----------------
#define CAP 256
__global__ __launch_bounds__(256) void knn_kernel(
    const float* __restrict__ pos,
    const int* __restrict__ samp,
    int* __restrict__ nbr,
    int* __restrict__ cntbuf)
{
    const int wave = threadIdx.x >> 6;
    const int lane = threadIdx.x & 63;
    const int c = blockIdx.x * 4 + wave;
    const int b = c >> 11;
    const float* pb = pos + (size_t)b * NN * 3;

    __shared__ float sd2[4][CAP];
    __shared__ int   sid[4][CAP];

    const int ctr = samp[c];
    const float cx = pb[ctr * 3 + 0];
    const float cy = pb[ctr * 3 + 1];
    const float cz = pb[ctr * 3 + 2];
    const float R2 = (float)(0.1 * 0.1);

    int cnt = 0;
    for (int r = 0; r < NN / 64; ++r) {
        const int g = r * 64 + lane;
        float dx = __fsub_rn(cx, pb[g * 3 + 0]);
        float dy = __fsub_rn(cy, pb[g * 3 + 1]);
        float dz = __fsub_rn(cz, pb[g * 3 + 2]);
        float d2 = __fadd_rn(__fadd_rn(__fmul_rn(dx, dx), __fmul_rn(dy, dy)),
                             __fmul_rn(dz, dz));
        const bool pred = (d2 <= R2);
        const unsigned long long mask = __ballot(pred);
        const int before = __popcll(mask & ((1ull << lane) - 1ull));
        if (pred) {
            const int slot = cnt + before;
            if (slot < CAP) { sd2[wave][slot] = d2; sid[wave][slot] = g; }
        }
        cnt += __popcll(mask);
    }
    if (cnt > CAP) cnt = CAP;
    __syncthreads();

    for (int ci = lane; ci < cnt; ci += 64) {
        const float dc = sd2[wave][ci];
        const int   ic = sid[wave][ci];
        int rank = 0;
        for (int j = 0; j < cnt; ++j) {
            const float dj = sd2[wave][j];
            const int   ij = sid[wave][j];
            rank += (dj < dc || (dj == dc && ij < ic)) ? 1 : 0;
        }
        if (rank < KK) nbr[c * KK + rank] = ic;
    }
    if (lane == 0) cntbuf[c] = (cnt < KK) ? cnt : KK;
}

// ---------------- Kernel 3: gather + MLP + max-pool, one wave per center ----
__global__ __launch_bounds__(256) void mlp_kernel(
    const float* __restrict__ x,
    const float* __restrict__ pos,
    const float* __restrict__ W1,
    const float* __restrict__ b1,
    const float* __restrict__ W2,
    const float* __restrict__ b2,
    const int* __restrict__ nbr,
    const int* __restrict__ cntbuf,
    const float* __restrict__ centers,
    float* __restrict__ out)
{
    __shared__ float WT[64 * 68];
    __shared__ float featL[4][32 * 68];

    const int tid = threadIdx.x, wave = tid >> 6, lane = tid & 63;
    const int c = blockIdx.x * 4 + wave;
    const int b = c >> 11;
    const int cnt = cntbuf[c];

    for (int idx = tid; idx < 67 * 64; idx += 256) {
        const int i = idx >> 6, h = idx & 63;
        WT[h * 68 + i] = W1[idx];
    }
    if (tid < 64) WT[tid * 68 + 67] = 0.0f;

    const float ctr0 = centers[c * 3 + 0];
    const float ctr1 = centers[c * 3 + 1];
    const float ctr2 = centers[c * 3 + 2];
    for (int k = 0; k < cnt; ++k) {
        const int j = nbr[c * KK + k];
        featL[wave][k * 68 + lane] = x[((size_t)b * NN + j) * FF + lane];
        if (lane < 3) {
            const float pj = pos[((size_t)b * NN + j) * 3 + lane];
            const float ci = (lane == 0) ? ctr0 : ((lane == 1) ? ctr1 : ctr2);
            featL[wave][k * 68 + 64 + lane] = __fsub_rn(pj, ci);
        }
        if (lane == 3) featL[wave][k * 68 + 67] = 0.0f;
    }
    __syncthreads();

    float wreg[68];
#pragma unroll
    for (int i4 = 0; i4 < 17; ++i4) {
        const float4 v = *(const float4*)&WT[lane * 68 + i4 * 4];
        wreg[i4 * 4 + 0] = v.x; wreg[i4 * 4 + 1] = v.y;
        wreg[i4 * 4 + 2] = v.z; wreg[i4 * 4 + 3] = v.w;
    }
    const float bias1 = b1[lane];
    for (int k = 0; k < cnt; ++k) {
        float acc = bias1;
#pragma unroll
        for (int i4 = 0; i4 < 17; ++i4) {
            const float4 f = *(const float4*)&featL[wave][k * 68 + i4 * 4];
            acc = fmaf(f.x, wreg[i4 * 4 + 0], acc);
            acc = fmaf(f.y, wreg[i4 * 4 + 1], acc);
            acc = fmaf(f.z, wreg[i4 * 4 + 2], acc);
            acc = fmaf(f.w, wreg[i4 * 4 + 3], acc);
        }
        featL[wave][k * 68 + lane] = fmaxf(acc, 0.0f);
    }
    __syncthreads();

    for (int idx = tid; idx < 64 * 64; idx += 256) {
        const int i = idx >> 6, h = idx & 63;
        WT[h * 68 + i] = W2[idx];
    }
    __syncthreads();

#pragma unroll
    for (int i4 = 0; i4 < 16; ++i4) {
        const float4 v = *(const float4*)&WT[lane * 68 + i4 * 4];
        wreg[i4 * 4 + 0] = v.x; wreg[i4 * 4 + 1] = v.y;
        wreg[i4 * 4 + 2] = v.z; wreg[i4 * 4 + 3] = v.w;
    }
    const float bias2 = b2[lane];
    float m = -INFINITY;
    for (int k = 0; k < cnt; ++k) {
        float acc = bias2;
#pragma unroll
        for (int i4 = 0; i4 < 16; ++i4) {
            const float4 f = *(const float4*)&featL[wave][k * 68 + i4 * 4];
            acc = fmaf(f.x, wreg[i4 * 4 + 0], acc);
            acc = fmaf(f.y, wreg[i4 * 4 + 1], acc);
            acc = fmaf(f.z, wreg[i4 * 4 + 2], acc);
            acc = fmaf(f.w, wreg[i4 * 4 + 3], acc);
        }
        m = fmaxf(m, fmaxf(acc, 0.0f));
    }
    out[(size_t)c * HH + lane] = (cnt > 0) ? m : 0.0f;
}

extern "C" void kernel_launch(void* const* d_in, const int* in_sizes, int n_in,
                              void* d_out, int out_size, void* d_ws, size_t ws_size,
                              hipStream_t stream) {
    const float* x   = (const float*)d_in[0];
    const float* pos = (const float*)d_in[1];
    const float* W1  = (const float*)d_in[3];
    const float* b1  = (const float*)d_in[4];
    const float* W2  = (const float*)d_in[5];
    const float* b2  = (const float*)d_in[6];

    float* out         = (float*)d_out;
    float* centers_out = out + (size_t)NB * MM * HH;
    float* batch_out   = centers_out + (size_t)NB * MM * 3;

    char* ws = (char*)d_ws;
    int* samp   = (int*)ws;                                   // 32 KB
    int* cntbuf = (int*)(ws + (size_t)NB * MM * 4);           // 32 KB
    int* nbr    = (int*)(ws + (size_t)2 * NB * MM * 4);       // 1 MB
    u64* syncW  = (u64*)(ws + (size_t)2 * NB * MM * 4
                            + (size_t)NB * MM * KK * 4);      // 256 B

    zero_sync_kernel<<<1, 64, 0, stream>>>(syncW);
    fps_kernel<<<NB * FB, FTH, 0, stream>>>(pos, syncW, samp, centers_out, batch_out);
    knn_kernel<<<(NB * MM) / 4, 256, 0, stream>>>(pos, samp, nbr, cntbuf);
    mlp_kernel<<<(NB * MM) / 4, 256, 0, stream>>>(x, pos, W1, b1, W2, b2,
                                                  nbr, cntbuf, centers_out, out);
}

// Round 9
// 2763.627 us; speedup vs baseline: 3.4518x; 3.4518x over previous
//
#include <hip/hip_runtime.h>
#include <hip/hip_bf16.h>
#include <float.h>
#include <math.h>

#define NB 4
#define NN 8192
#define FF 64
#define MM 2048
#define KK 32
#define HH 64

#define FT 512          // fps threads (8 waves)
#define RPT 8           // points per thread in registers
#define LPT 8           // points per thread from LDS

// 2-wide DPP argmax (value, orig idx), tie -> lower idx; lane63 gets winner.
// identities: v=-inf, oi=INT_MAX. (validated rounds 2-3)
#define DPP2_STEP(bv, boi, ctrl, rmask)                                         \
    {                                                                           \
        int _v  = __builtin_amdgcn_update_dpp((int)0xff800000,                  \
                      __float_as_int(bv), (ctrl), (rmask), 0xf, false);         \
        int _oi = __builtin_amdgcn_update_dpp((int)0x7fffffff,                  \
                      (boi), (ctrl), (rmask), 0xf, false);                      \
        float _vf = __int_as_float(_v);                                         \
        if (_vf > (bv) || (_vf == (bv) && _oi < (boi))) { (bv) = _vf; (boi) = _oi; } \
    }
#define DPP2_REDUCE(bv, boi)            \
    DPP2_STEP(bv, boi, 0x111, 0xf)      \
    DPP2_STEP(bv, boi, 0x112, 0xf)      \
    DPP2_STEP(bv, boi, 0x114, 0xf)      \
    DPP2_STEP(bv, boi, 0x118, 0xf)      \
    DPP2_STEP(bv, boi, 0x142, 0xa)      \
    DPP2_STEP(bv, boi, 0x143, 0xc)

// comparator for (value, idx-bits) in float2: max value, tie -> lower idx
__device__ __forceinline__ float2 argmax2(float2 a, float2 b) {
    const int ia = __float_as_int(a.y), ib = __float_as_int(b.y);
    return (b.x > a.x || (b.x == a.x && ib < ia)) ? b : a;
}

// ---------------- Kernel 1: exact FPS, hybrid reg/LDS point store ----------------
__global__ __launch_bounds__(FT) void fps_kernel(
    const float* __restrict__ pos,
    int* __restrict__ samp,
    float* __restrict__ centers_out,
    float* __restrict__ batch_out)
{
    __shared__ float4 pts4[NN];          // all points, natural order (128 KB)
    __shared__ float2 slots[2][8];       // parity-buffered per-wave winners

    const int b = blockIdx.x;
    const float* pb = pos + (size_t)b * NN * 3;
    const int tid = threadIdx.x;
    const int w   = tid >> 6;
    const int lane = tid & 63;

    // ---- stage all points into LDS float4 (natural order: slot == index) ----
    for (int j = tid; j < NN; j += FT)
        pts4[j] = make_float4(pb[j * 3 + 0], pb[j * 3 + 1], pb[j * 3 + 2], 0.0f);
    for (int j = tid; j < MM; j += FT) batch_out[b * MM + j] = (float)b;
    __syncthreads();

    // ---- register half: points tid + i*FT, i in [0,8) (indices 0..4095) ----
    float px[RPT], py[RPT], pz[RPT];
    float dist[RPT + LPT];
#pragma unroll
    for (int i = 0; i < RPT; ++i) {
        const float4 p = pts4[i * FT + tid];
        px[i] = p.x; py[i] = p.y; pz[i] = p.z;
        dist[i] = INFINITY;
    }
#pragma unroll
    for (int i = 0; i < LPT; ++i) dist[RPT + i] = INFINITY;

    int   cur = 0;
    float lx = pb[0], ly = pb[1], lz = pb[2];

    for (int s = 0; s < MM; ++s) {
        if (tid == 0) {
            samp[b * MM + s] = cur;
            centers_out[((size_t)b * MM + s) * 3 + 0] = lx;
            centers_out[((size_t)b * MM + s) * 3 + 1] = ly;
            centers_out[((size_t)b * MM + s) * 3 + 2] = lz;
        }
        if (s == MM - 1) break;   // last argmax unused by the reference

        float bv = -INFINITY;
        int   bi = 0x7fffffff;

        // ---- register half (indices ascending: tid, tid+512, ... tid+3584) ----
#pragma unroll
        for (int i = 0; i < RPT; ++i) {
            // exact ref arithmetic: ((dx*dx + dy*dy) + dz*dz), no FMA contraction
            const float dx = __fsub_rn(px[i], lx);
            const float dy = __fsub_rn(py[i], ly);
            const float dz = __fsub_rn(pz[i], lz);
            const float d  = __fadd_rn(__fadd_rn(__fmul_rn(dx, dx),
                                                 __fmul_rn(dy, dy)),
                                       __fmul_rn(dz, dz));
            const float nd = fminf(dist[i], d);
            dist[i] = nd;
            if (nd > bv) { bv = nd; bi = i * FT + tid; }
        }
        // ---- LDS half (indices 4096+tid+i*512, ascending, all > reg half) ----
#pragma unroll
        for (int i = 0; i < LPT; ++i) {
            const int g = (NN / 2) + i * FT + tid;
            const float4 p = pts4[g];             // contiguous b128: conflict-free
            const float dx = __fsub_rn(p.x, lx);
            const float dy = __fsub_rn(p.y, ly);
            const float dz = __fsub_rn(p.z, lz);
            const float d  = __fadd_rn(__fadd_rn(__fmul_rn(dx, dx),
                                                 __fmul_rn(dy, dy)),
                                       __fmul_rn(dz, dz));
            const float nd = fminf(dist[RPT + i], d);
            dist[RPT + i] = nd;
            if (nd > bv) { bv = nd; bi = g; }
        }

        // ---- wave argmax (DPP), per-wave slot, one barrier, tree scan ----
        DPP2_REDUCE(bv, bi)
        const int par = s & 1;
        if (lane == 63) slots[par][w] = make_float2(bv, __int_as_float(bi));
        __syncthreads();

        const float2 s0 = slots[par][0], s1 = slots[par][1];
        const float2 s2 = slots[par][2], s3 = slots[par][3];
        const float2 s4 = slots[par][4], s5 = slots[par][5];
        const float2 s6 = slots[par][6], s7 = slots[par][7];
        const float2 a0 = argmax2(s0, s1), a1 = argmax2(s2, s3);
        const float2 a2 = argmax2(s4, s5), a3 = argmax2(s6, s7);
        const float2 b0 = argmax2(a0, a1), b1 = argmax2(a2, a3);
        const float2 win = argmax2(b0, b1);

        cur = __float_as_int(win.y);
        const float4 wp = pts4[cur];             // broadcast read, conflict-free
        lx = wp.x; ly = wp.y; lz = wp.z;
    }
}

// ---------------- Kernel 2: radius-KNN, one wave per center ----------------
#define CAP 256
__global__ __launch_bounds__(256) void knn_kernel(
    const float* __restrict__ pos,
    const int* __restrict__ samp,
    int* __restrict__ nbr,
    int* __restrict__ cntbuf)
{
    const int wave = threadIdx.x >> 6;
    const int lane = threadIdx.x & 63;
    const int c = blockIdx.x * 4 + wave;
    const int b = c >> 11;
    const float* pb = pos + (size_t)b * NN * 3;

    __shared__ float sd2[4][CAP];
    __shared__ int   sid[4][CAP];

    const int ctr = samp[c];
    const float cx = pb[ctr * 3 + 0];
    const float cy = pb[ctr * 3 + 1];
    const float cz = pb[ctr * 3 + 2];
    const float R2 = (float)(0.1 * 0.1);

    int cnt = 0;
    for (int r = 0; r < NN / 64; ++r) {
        const int g = r * 64 + lane;
        float dx = __fsub_rn(cx, pb[g * 3 + 0]);
        float dy = __fsub_rn(cy, pb[g * 3 + 1]);
        float dz = __fsub_rn(cz, pb[g * 3 + 2]);
        float d2 = __fadd_rn(__fadd_rn(__fmul_rn(dx, dx), __fmul_rn(dy, dy)),
                             __fmul_rn(dz, dz));
        const bool pred = (d2 <= R2);
        const unsigned long long mask = __ballot(pred);
        const int before = __popcll(mask & ((1ull << lane) - 1ull));
        if (pred) {
            const int slot = cnt + before;
            if (slot < CAP) { sd2[wave][slot] = d2; sid[wave][slot] = g; }
        }
        cnt += __popcll(mask);
    }
    if (cnt > CAP) cnt = CAP;
    __syncthreads();

    for (int ci = lane; ci < cnt; ci += 64) {
        const float dc = sd2[wave][ci];
        const int   ic = sid[wave][ci];
        int rank = 0;
        for (int j = 0; j < cnt; ++j) {
            const float dj = sd2[wave][j];
            const int   ij = sid[wave][j];
            rank += (dj < dc || (dj == dc && ij < ic)) ? 1 : 0;
        }
        if (rank < KK) nbr[c * KK + rank] = ic;
    }
    if (lane == 0) cntbuf[c] = (cnt < KK) ? cnt : KK;
}

// ---------------- Kernel 3: gather + MLP + max-pool, one wave per center ----
__global__ __launch_bounds__(256) void mlp_kernel(
    const float* __restrict__ x,
    const float* __restrict__ pos,
    const float* __restrict__ W1,
    const float* __restrict__ b1,
    const float* __restrict__ W2,
    const float* __restrict__ b2,
    const int* __restrict__ nbr,
    const int* __restrict__ cntbuf,
    const float* __restrict__ centers,
    float* __restrict__ out)
{
    __shared__ float WT[64 * 68];
    __shared__ float featL[4][32 * 68];

    const int tid = threadIdx.x, wave = tid >> 6, lane = tid & 63;
    const int c = blockIdx.x * 4 + wave;
    const int b = c >> 11;
    const int cnt = cntbuf[c];

    for (int idx = tid; idx < 67 * 64; idx += 256) {
        const int i = idx >> 6, h = idx & 63;
        WT[h * 68 + i] = W1[idx];
    }
    if (tid < 64) WT[tid * 68 + 67] = 0.0f;

    const float ctr0 = centers[c * 3 + 0];
    const float ctr1 = centers[c * 3 + 1];
    const float ctr2 = centers[c * 3 + 2];
    for (int k = 0; k < cnt; ++k) {
        const int j = nbr[c * KK + k];
        featL[wave][k * 68 + lane] = x[((size_t)b * NN + j) * FF + lane];
        if (lane < 3) {
            const float pj = pos[((size_t)b * NN + j) * 3 + lane];
            const float ci = (lane == 0) ? ctr0 : ((lane == 1) ? ctr1 : ctr2);
            featL[wave][k * 68 + 64 + lane] = __fsub_rn(pj, ci);
        }
        if (lane == 3) featL[wave][k * 68 + 67] = 0.0f;
    }
    __syncthreads();

    float wreg[68];
#pragma unroll
    for (int i4 = 0; i4 < 17; ++i4) {
        const float4 v = *(const float4*)&WT[lane * 68 + i4 * 4];
        wreg[i4 * 4 + 0] = v.x; wreg[i4 * 4 + 1] = v.y;
        wreg[i4 * 4 + 2] = v.z; wreg[i4 * 4 + 3] = v.w;
    }
    const float bias1 = b1[lane];
    for (int k = 0; k < cnt; ++k) {
        float acc = bias1;
#pragma unroll
        for (int i4 = 0; i4 < 17; ++i4) {
            const float4 f = *(const float4*)&featL[wave][k * 68 + i4 * 4];
            acc = fmaf(f.x, wreg[i4 * 4 + 0], acc);
            acc = fmaf(f.y, wreg[i4 * 4 + 1], acc);
            acc = fmaf(f.z, wreg[i4 * 4 + 2], acc);
            acc = fmaf(f.w, wreg[i4 * 4 + 3], acc);
        }
        featL[wave][k * 68 + lane] = fmaxf(acc, 0.0f);
    }
    __syncthreads();

    for (int idx = tid; idx < 64 * 64; idx += 256) {
        const int i = idx >> 6, h = idx & 63;
        WT[h * 68 + i] = W2[idx];
    }
    __syncthreads();

#pragma unroll
    for (int i4 = 0; i4 < 16; ++i4) {
        const float4 v = *(const float4*)&WT[lane * 68 + i4 * 4];
        wreg[i4 * 4 + 0] = v.x; wreg[i4 * 4 + 1] = v.y;
        wreg[i4 * 4 + 2] = v.z; wreg[i4 * 4 + 3] = v.w;
    }
    const float bias2 = b2[lane];
    float m = -INFINITY;
    for (int k = 0; k < cnt; ++k) {
        float acc = bias2;
#pragma unroll
        for (int i4 = 0; i4 < 16; ++i4) {
            const float4 f = *(const float4*)&featL[wave][k * 68 + i4 * 4];
            acc = fmaf(f.x, wreg[i4 * 4 + 0], acc);
            acc = fmaf(f.y, wreg[i4 * 4 + 1], acc);
            acc = fmaf(f.z, wreg[i4 * 4 + 2], acc);
            acc = fmaf(f.w, wreg[i4 * 4 + 3], acc);
        }
        m = fmaxf(m, fmaxf(acc, 0.0f));
    }
    out[(size_t)c * HH + lane] = (cnt > 0) ? m : 0.0f;
}

extern "C" void kernel_launch(void* const* d_in, const int* in_sizes, int n_in,
                              void* d_out, int out_size, void* d_ws, size_t ws_size,
                              hipStream_t stream) {
    const float* x   = (const float*)d_in[0];
    const float* pos = (const float*)d_in[1];
    const float* W1  = (const float*)d_in[3];
    const float* b1  = (const float*)d_in[4];
    const float* W2  = (const float*)d_in[5];
    const float* b2  = (const float*)d_in[6];

    float* out         = (float*)d_out;
    float* centers_out = out + (size_t)NB * MM * HH;
    float* batch_out   = centers_out + (size_t)NB * MM * 3;

    char* ws = (char*)d_ws;
    int* samp   = (int*)ws;
    int* cntbuf = (int*)(ws + (size_t)NB * MM * 4);
    int* nbr    = (int*)(ws + (size_t)2 * NB * MM * 4);

    fps_kernel<<<NB, FT, 0, stream>>>(pos, samp, centers_out, batch_out);
    knn_kernel<<<(NB * MM) / 4, 256, 0, stream>>>(pos, samp, nbr, cntbuf);
    mlp_kernel<<<(NB * MM) / 4, 256, 0, stream>>>(x, pos, W1, b1, W2, b2,
                                                  nbr, cntbuf, centers_out, out);
}

// Round 10
// 2624.205 us; speedup vs baseline: 3.6352x; 1.0531x over previous
//
#include <hip/hip_runtime.h>
#include <hip/hip_bf16.h>
#include <float.h>
#include <math.h>

#define NB 4
#define NN 8192
#define FF 64
#define MM 2048
#define KK 32
#define HH 64

#define FT 512          // fps threads (8 waves)
#define PPT 16          // points per thread, all register-resident

typedef float v2f __attribute__((ext_vector_type(2)));

// 2-wide DPP argmax (value, orig idx), tie -> lower idx; lane63 gets winner.
// identities: v=-inf, oi=INT_MAX. (validated rounds 2/3/9)
#define DPP2_STEP(bv, boi, ctrl, rmask)                                         \
    {                                                                           \
        int _v  = __builtin_amdgcn_update_dpp((int)0xff800000,                  \
                      __float_as_int(bv), (ctrl), (rmask), 0xf, false);         \
        int _oi = __builtin_amdgcn_update_dpp((int)0x7fffffff,                  \
                      (boi), (ctrl), (rmask), 0xf, false);                      \
        float _vf = __int_as_float(_v);                                         \
        if (_vf > (bv) || (_vf == (bv) && _oi < (boi))) { (bv) = _vf; (boi) = _oi; } \
    }
#define DPP2_REDUCE(bv, boi)            \
    DPP2_STEP(bv, boi, 0x111, 0xf)      \
    DPP2_STEP(bv, boi, 0x112, 0xf)      \
    DPP2_STEP(bv, boi, 0x114, 0xf)      \
    DPP2_STEP(bv, boi, 0x118, 0xf)      \
    DPP2_STEP(bv, boi, 0x142, 0xa)      \
    DPP2_STEP(bv, boi, 0x143, 0xc)

// comparator for (value, idx-bits) in float2: max value, tie -> lower idx
__device__ __forceinline__ float2 argmax2(float2 a, float2 b) {
    const int ia = __float_as_int(a.y), ib = __float_as_int(b.y);
    return (b.x > a.x || (b.x == a.x && ib < ia)) ? b : a;
}

// ---------------- Kernel 1: exact FPS, packed-FP32 register loop ----------------
__global__ __launch_bounds__(FT) void fps_kernel(
    const float* __restrict__ pos,
    int* __restrict__ samp,
    float* __restrict__ centers_out,
    float* __restrict__ batch_out)
{
#pragma clang fp contract(off)
    __shared__ float4 pts4[NN];          // natural order; winner-fetch only (128 KB)
    __shared__ float2 slots[2][8];       // parity-buffered per-wave winners

    const int b = blockIdx.x;
    const float* pb = pos + (size_t)b * NN * 3;
    const int tid = threadIdx.x;
    const int w   = tid >> 6;
    const int lane = tid & 63;

    // ---- stage points (for winner fetch); prefill batch ids ----
    for (int j = tid; j < NN; j += FT)
        pts4[j] = make_float4(pb[j * 3 + 0], pb[j * 3 + 1], pb[j * 3 + 2], 0.0f);
    for (int j = tid; j < MM; j += FT) batch_out[b * MM + j] = (float)b;
    __syncthreads();

    // ---- all 16 points in registers as 8 packed pairs ----
    // pair j holds indices (2j)*FT+tid (lane .x) and (2j+1)*FT+tid (lane .y)
    v2f pxv[8], pyv[8], pzv[8], dv[8];
#pragma unroll
    for (int j = 0; j < 8; ++j) {
        const float4 p0 = pts4[(2 * j) * FT + tid];
        const float4 p1 = pts4[(2 * j + 1) * FT + tid];
        pxv[j] = (v2f){p0.x, p1.x};
        pyv[j] = (v2f){p0.y, p1.y};
        pzv[j] = (v2f){p0.z, p1.z};
        dv[j]  = (v2f){INFINITY, INFINITY};
    }

    int   cur = 0;
    float lx = pb[0], ly = pb[1], lz = pb[2];

    for (int s = 0; s < MM; ++s) {
#pragma clang fp contract(off)
        if (tid == 0) {
            samp[b * MM + s] = cur;
            centers_out[((size_t)b * MM + s) * 3 + 0] = lx;
            centers_out[((size_t)b * MM + s) * 3 + 1] = ly;
            centers_out[((size_t)b * MM + s) * 3 + 2] = lz;
        }
        if (s == MM - 1) break;   // last argmax unused by the reference

        const v2f l2x = (v2f){lx, lx};
        const v2f l2y = (v2f){ly, ly};
        const v2f l2z = (v2f){lz, lz};

        float bv = -INFINITY;
        int   bi = 0x7fffffff;
        // ---- packed distance update: componentwise IEEE sub/mul/add, no FMA
        //      (contract off) => bit-identical to ((dx*dx + dy*dy) + dz*dz) ----
#pragma unroll
        for (int j = 0; j < 8; ++j) {
            const v2f dx = pxv[j] - l2x;
            const v2f dy = pyv[j] - l2y;
            const v2f dz = pzv[j] - l2z;
            const v2f d2 = (dx * dx + dy * dy) + dz * dz;
            v2f nd;
            nd.x = fminf(dv[j].x, d2.x);
            nd.y = fminf(dv[j].y, d2.y);
            dv[j] = nd;
            // ascending index order: (2j)*FT+tid < (2j+1)*FT+tid; strict >
            if (nd.x > bv) { bv = nd.x; bi = (2 * j) * FT + tid; }
            if (nd.y > bv) { bv = nd.y; bi = (2 * j + 1) * FT + tid; }
        }

        // ---- wave argmax (DPP), per-wave slot, one barrier, tree scan ----
        DPP2_REDUCE(bv, bi)
        const int par = s & 1;
        if (lane == 63) slots[par][w] = make_float2(bv, __int_as_float(bi));
        __syncthreads();

        const float2 s0 = slots[par][0], s1 = slots[par][1];
        const float2 s2 = slots[par][2], s3 = slots[par][3];
        const float2 s4 = slots[par][4], s5 = slots[par][5];
        const float2 s6 = slots[par][6], s7 = slots[par][7];
        const float2 a0 = argmax2(s0, s1), a1 = argmax2(s2, s3);
        const float2 a2 = argmax2(s4, s5), a3 = argmax2(s6, s7);
        const float2 b0 = argmax2(a0, a1), b1 = argmax2(a2, a3);
        const float2 win = argmax2(b0, b1);

        cur = __float_as_int(win.y);
        const float4 wp = pts4[cur];             // broadcast read, conflict-free
        lx = wp.x; ly = wp.y; lz = wp.z;
    }
}

// ---------------- Kernel 2: radius-KNN, one wave per center ----------------
#define CAP 256
__global__ __launch_bounds__(256) void knn_kernel(
    const float* __restrict__ pos,
    const int* __restrict__ samp,
    int* __restrict__ nbr,
    int* __restrict__ cntbuf)
{
    const int wave = threadIdx.x >> 6;
    const int lane = threadIdx.x & 63;
    const int c = blockIdx.x * 4 + wave;
    const int b = c >> 11;
    const float* pb = pos + (size_t)b * NN * 3;

    __shared__ float sd2[4][CAP];
    __shared__ int   sid[4][CAP];

    const int ctr = samp[c];
    const float cx = pb[ctr * 3 + 0];
    const float cy = pb[ctr * 3 + 1];
    const float cz = pb[ctr * 3 + 2];
    const float R2 = (float)(0.1 * 0.1);

    int cnt = 0;
    for (int r = 0; r < NN / 64; ++r) {
        const int g = r * 64 + lane;
        float dx = __fsub_rn(cx, pb[g * 3 + 0]);
        float dy = __fsub_rn(cy, pb[g * 3 + 1]);
        float dz = __fsub_rn(cz, pb[g * 3 + 2]);
        float d2 = __fadd_rn(__fadd_rn(__fmul_rn(dx, dx), __fmul_rn(dy, dy)),
                             __fmul_rn(dz, dz));
        const bool pred = (d2 <= R2);
        const unsigned long long mask = __ballot(pred);
        const int before = __popcll(mask & ((1ull << lane) - 1ull));
        if (pred) {
            const int slot = cnt + before;
            if (slot < CAP) { sd2[wave][slot] = d2; sid[wave][slot] = g; }
        }
        cnt += __popcll(mask);
    }
    if (cnt > CAP) cnt = CAP;
    __syncthreads();

    for (int ci = lane; ci < cnt; ci += 64) {
        const float dc = sd2[wave][ci];
        const int   ic = sid[wave][ci];
        int rank = 0;
        for (int j = 0; j < cnt; ++j) {
            const float dj = sd2[wave][j];
            const int   ij = sid[wave][j];
            rank += (dj < dc || (dj == dc && ij < ic)) ? 1 : 0;
        }
        if (rank < KK) nbr[c * KK + rank] = ic;
    }
    if (lane == 0) cntbuf[c] = (cnt < KK) ? cnt : KK;
}

// ---------------- Kernel 3: gather + MLP + max-pool, one wave per center ----
__global__ __launch_bounds__(256) void mlp_kernel(
    const float* __restrict__ x,
    const float* __restrict__ pos,
    const float* __restrict__ W1,
    const float* __restrict__ b1,
    const float* __restrict__ W2,
    const float* __restrict__ b2,
    const int* __restrict__ nbr,
    const int* __restrict__ cntbuf,
    const float* __restrict__ centers,
    float* __restrict__ out)
{
    __shared__ float WT[64 * 68];
    __shared__ float featL[4][32 * 68];

    const int tid = threadIdx.x, wave = tid >> 6, lane = tid & 63;
    const int c = blockIdx.x * 4 + wave;
    const int b = c >> 11;
    const int cnt = cntbuf[c];

    for (int idx = tid; idx < 67 * 64; idx += 256) {
        const int i = idx >> 6, h = idx & 63;
        WT[h * 68 + i] = W1[idx];
    }
    if (tid < 64) WT[tid * 68 + 67] = 0.0f;

    const float ctr0 = centers[c * 3 + 0];
    const float ctr1 = centers[c * 3 + 1];
    const float ctr2 = centers[c * 3 + 2];
    for (int k = 0; k < cnt; ++k) {
        const int j = nbr[c * KK + k];
        featL[wave][k * 68 + lane] = x[((size_t)b * NN + j) * FF + lane];
        if (lane < 3) {
            const float pj = pos[((size_t)b * NN + j) * 3 + lane];
            const float ci = (lane == 0) ? ctr0 : ((lane == 1) ? ctr1 : ctr2);
            featL[wave][k * 68 + 64 + lane] = __fsub_rn(pj, ci);
        }
        if (lane == 3) featL[wave][k * 68 + 67] = 0.0f;
    }
    __syncthreads();

    float wreg[68];
#pragma unroll
    for (int i4 = 0; i4 < 17; ++i4) {
        const float4 v = *(const float4*)&WT[lane * 68 + i4 * 4];
        wreg[i4 * 4 + 0] = v.x; wreg[i4 * 4 + 1] = v.y;
        wreg[i4 * 4 + 2] = v.z; wreg[i4 * 4 + 3] = v.w;
    }
    const float bias1 = b1[lane];
    for (int k = 0; k < cnt; ++k) {
        float acc = bias1;
#pragma unroll
        for (int i4 = 0; i4 < 17; ++i4) {
            const float4 f = *(const float4*)&featL[wave][k * 68 + i4 * 4];
            acc = fmaf(f.x, wreg[i4 * 4 + 0], acc);
            acc = fmaf(f.y, wreg[i4 * 4 + 1], acc);
            acc = fmaf(f.z, wreg[i4 * 4 + 2], acc);
            acc = fmaf(f.w, wreg[i4 * 4 + 3], acc);
        }
        featL[wave][k * 68 + lane] = fmaxf(acc, 0.0f);
    }
    __syncthreads();

    for (int idx = tid; idx < 64 * 64; idx += 256) {
        const int i = idx >> 6, h = idx & 63;
        WT[h * 68 + i] = W2[idx];
    }
    __syncthreads();

#pragma unroll
    for (int i4 = 0; i4 < 16; ++i4) {
        const float4 v = *(const float4*)&WT[lane * 68 + i4 * 4];
        wreg[i4 * 4 + 0] = v.x; wreg[i4 * 4 + 1] = v.y;
        wreg[i4 * 4 + 2] = v.z; wreg[i4 * 4 + 3] = v.w;
    }
    const float bias2 = b2[lane];
    float m = -INFINITY;
    for (int k = 0; k < cnt; ++k) {
        float acc = bias2;
#pragma unroll
        for (int i4 = 0; i4 < 16; ++i4) {
            const float4 f = *(const float4*)&featL[wave][k * 68 + i4 * 4];
            acc = fmaf(f.x, wreg[i4 * 4 + 0], acc);
            acc = fmaf(f.y, wreg[i4 * 4 + 1], acc);
            acc = fmaf(f.z, wreg[i4 * 4 + 2], acc);
            acc = fmaf(f.w, wreg[i4 * 4 + 3], acc);
        }
        m = fmaxf(m, fmaxf(acc, 0.0f));
    }
    out[(size_t)c * HH + lane] = (cnt > 0) ? m : 0.0f;
}

extern "C" void kernel_launch(void* const* d_in, const int* in_sizes, int n_in,
                              void* d_out, int out_size, void* d_ws, size_t ws_size,
                              hipStream_t stream) {
    const float* x   = (const float*)d_in[0];
    const float* pos = (const float*)d_in[1];
    const float* W1  = (const float*)d_in[3];
    const float* b1  = (const float*)d_in[4];
    const float* W2  = (const float*)d_in[5];
    const float* b2  = (const float*)d_in[6];

    float* out         = (float*)d_out;
    float* centers_out = out + (size_t)NB * MM * HH;
    float* batch_out   = centers_out + (size_t)NB * MM * 3;

    char* ws = (char*)d_ws;
    int* samp   = (int*)ws;
    int* cntbuf = (int*)(ws + (size_t)NB * MM * 4);
    int* nbr    = (int*)(ws + (size_t)2 * NB * MM * 4);

    fps_kernel<<<NB, FT, 0, stream>>>(pos, samp, centers_out, batch_out);
    knn_kernel<<<(NB * MM) / 4, 256, 0, stream>>>(pos, samp, nbr, cntbuf);
    mlp_kernel<<<(NB * MM) / 4, 256, 0, stream>>>(x, pos, W1, b1, W2, b2,
                                                  nbr, cntbuf, centers_out, out);
}

// Round 11
// 2123.394 us; speedup vs baseline: 4.4926x; 1.2359x over previous
//
#include <hip/hip_runtime.h>
#include <hip/hip_bf16.h>
#include <float.h>
#include <math.h>

#define NB 4
#define NN 8192
#define FF 64
#define MM 2048
#define KK 32
#define HH 64

#define FT 512          // fps threads (8 waves)

typedef float v2f __attribute__((ext_vector_type(2)));

// DPP float-max step (old = -inf identity), validated r4.
#define DPP_FMAX(v, ctrl, rmask)                                                \
    { int _t = __builtin_amdgcn_update_dpp((int)0xff800000, __float_as_int(v),  \
                   (ctrl), (rmask), 0xf, false);                                \
      (v) = fmaxf((v), __int_as_float(_t)); }
#define DPP_FMAX6(v)  DPP_FMAX(v,0x111,0xf) DPP_FMAX(v,0x112,0xf) \
                      DPP_FMAX(v,0x114,0xf) DPP_FMAX(v,0x118,0xf) \
                      DPP_FMAX(v,0x142,0xa) DPP_FMAX(v,0x143,0xc)

// DPP int-min step (old = INT_MAX identity).
#define DPP_IMIN(v, ctrl, rmask)                                                \
    { int _t = __builtin_amdgcn_update_dpp((int)0x7fffffff, (v),                \
                   (ctrl), (rmask), 0xf, false);                                \
      (v) = min((v), _t); }
#define DPP_IMIN6(v)  DPP_IMIN(v,0x111,0xf) DPP_IMIN(v,0x112,0xf) \
                      DPP_IMIN(v,0x114,0xf) DPP_IMIN(v,0x118,0xf) \
                      DPP_IMIN(v,0x142,0xa) DPP_IMIN(v,0x143,0xc)

// ---------------- Kernel 1: exact FPS, two-phase value/index argmax ----------------
__global__ __launch_bounds__(FT) void fps_kernel(
    const float* __restrict__ pos,
    int* __restrict__ samp,
    float* __restrict__ centers_out,
    float* __restrict__ batch_out)
{
#pragma clang fp contract(off)
    __shared__ float4 pts4[NN];          // natural order; winner-fetch only (128 KB)
    __shared__ float vslot[2][8];        // parity per-wave value maxes
    __shared__ int   islot[2][8];        // parity per-wave min matching idx

    const int b = blockIdx.x;
    const float* pb = pos + (size_t)b * NN * 3;
    const int tid = threadIdx.x;
    const int w   = tid >> 6;
    const int lane = tid & 63;

    // ---- stage points; prefill batch ids ----
    for (int j = tid; j < NN; j += FT)
        pts4[j] = make_float4(pb[j * 3 + 0], pb[j * 3 + 1], pb[j * 3 + 2], 0.0f);
    for (int j = tid; j < MM; j += FT) batch_out[b * MM + j] = (float)b;
    __syncthreads();

    // ---- all 16 points in registers as 8 packed pairs ----
    // pair j: indices (2j)*FT+tid (.x) and (2j+1)*FT+tid (.y)
    v2f pxv[8], pyv[8], pzv[8], dv[8];
#pragma unroll
    for (int j = 0; j < 8; ++j) {
        const float4 p0 = pts4[(2 * j) * FT + tid];
        const float4 p1 = pts4[(2 * j + 1) * FT + tid];
        pxv[j] = (v2f){p0.x, p1.x};
        pyv[j] = (v2f){p0.y, p1.y};
        pzv[j] = (v2f){p0.z, p1.z};
        dv[j]  = (v2f){INFINITY, INFINITY};
    }

    int   cur = 0;
    float lx = pb[0], ly = pb[1], lz = pb[2];

    for (int s = 0; s < MM; ++s) {
#pragma clang fp contract(off)
        if (tid == 0) {
            samp[b * MM + s] = cur;
            centers_out[((size_t)b * MM + s) * 3 + 0] = lx;
            centers_out[((size_t)b * MM + s) * 3 + 1] = ly;
            centers_out[((size_t)b * MM + s) * 3 + 2] = lz;
        }
        if (s == MM - 1) break;   // last argmax unused by the reference

        const v2f l2x = (v2f){lx, lx};
        const v2f l2y = (v2f){ly, ly};
        const v2f l2z = (v2f){lz, lz};

        // ---- phase 1: distance update + VALUE-ONLY max (packed ops) ----
        v2f vmax2 = (v2f){-INFINITY, -INFINITY};
#pragma unroll
        for (int j = 0; j < 8; ++j) {
            const v2f dx = pxv[j] - l2x;
            const v2f dy = pyv[j] - l2y;
            const v2f dz = pzv[j] - l2z;
            const v2f d2 = (dx * dx + dy * dy) + dz * dz;   // exact: contract off
            dv[j] = __builtin_elementwise_min(dv[j], d2);   // jnp.minimum, exact
            vmax2 = __builtin_elementwise_max(vmax2, dv[j]);
        }
        const float tv = fmaxf(vmax2.x, vmax2.y);           // thread value max

        float wv = tv;
        DPP_FMAX6(wv)                                       // lane63: wave max
        const int par = s & 1;
        if (lane == 63) vslot[par][w] = wv;
        __syncthreads();

        const float4 v0 = *(const float4*)&vslot[par][0];
        const float4 v1 = *(const float4*)&vslot[par][4];
        const float V = fmaxf(fmaxf(fmaxf(v0.x, v0.y), fmaxf(v0.z, v0.w)),
                              fmaxf(fmaxf(v1.x, v1.y), fmaxf(v1.z, v1.w)));

        // ---- phase 2: rare index recovery (exec-sparse; usually 1 thread) ----
        int cand = 0x7fffffff;
        if (tv == V) {
            // scan stored dists for exact match; ascending index order ->
            // branchless min keeps the LOWEST matching index (ref tie-break)
#pragma unroll
            for (int j = 0; j < 8; ++j) {
                if (dv[j].x == V) cand = min(cand, (2 * j) * FT + tid);
                if (dv[j].y == V) cand = min(cand, (2 * j + 1) * FT + tid);
            }
        }
        DPP_IMIN6(cand)                                     // lane63: wave min idx
        if (lane == 63) islot[par][w] = cand;
        __syncthreads();

        const int4 i0 = *(const int4*)&islot[par][0];
        const int4 i1 = *(const int4*)&islot[par][4];
        cur = min(min(min(i0.x, i0.y), min(i0.z, i0.w)),
                  min(min(i1.x, i1.y), min(i1.z, i1.w)));

        const float4 wp = pts4[cur];                        // broadcast, conflict-free
        lx = wp.x; ly = wp.y; lz = wp.z;
    }
}

// ---------------- Kernel 2: radius-KNN, one wave per center ----------------
#define CAP 256
__global__ __launch_bounds__(256) void knn_kernel(
    const float* __restrict__ pos,
    const int* __restrict__ samp,
    int* __restrict__ nbr,
    int* __restrict__ cntbuf)
{
    const int wave = threadIdx.x >> 6;
    const int lane = threadIdx.x & 63;
    const int c = blockIdx.x * 4 + wave;
    const int b = c >> 11;
    const float* pb = pos + (size_t)b * NN * 3;

    __shared__ float sd2[4][CAP];
    __shared__ int   sid[4][CAP];

    const int ctr = samp[c];
    const float cx = pb[ctr * 3 + 0];
    const float cy = pb[ctr * 3 + 1];
    const float cz = pb[ctr * 3 + 2];
    const float R2 = (float)(0.1 * 0.1);

    int cnt = 0;
    for (int r = 0; r < NN / 64; ++r) {
        const int g = r * 64 + lane;
        float dx = __fsub_rn(cx, pb[g * 3 + 0]);
        float dy = __fsub_rn(cy, pb[g * 3 + 1]);
        float dz = __fsub_rn(cz, pb[g * 3 + 2]);
        float d2 = __fadd_rn(__fadd_rn(__fmul_rn(dx, dx), __fmul_rn(dy, dy)),
                             __fmul_rn(dz, dz));
        const bool pred = (d2 <= R2);
        const unsigned long long mask = __ballot(pred);
        const int before = __popcll(mask & ((1ull << lane) - 1ull));
        if (pred) {
            const int slot = cnt + before;
            if (slot < CAP) { sd2[wave][slot] = d2; sid[wave][slot] = g; }
        }
        cnt += __popcll(mask);
    }
    if (cnt > CAP) cnt = CAP;
    __syncthreads();

    for (int ci = lane; ci < cnt; ci += 64) {
        const float dc = sd2[wave][ci];
        const int   ic = sid[wave][ci];
        int rank = 0;
        for (int j = 0; j < cnt; ++j) {
            const float dj = sd2[wave][j];
            const int   ij = sid[wave][j];
            rank += (dj < dc || (dj == dc && ij < ic)) ? 1 : 0;
        }
        if (rank < KK) nbr[c * KK + rank] = ic;
    }
    if (lane == 0) cntbuf[c] = (cnt < KK) ? cnt : KK;
}

// ---------------- Kernel 3: gather + MLP + max-pool, one wave per center ----
__global__ __launch_bounds__(256) void mlp_kernel(
    const float* __restrict__ x,
    const float* __restrict__ pos,
    const float* __restrict__ W1,
    const float* __restrict__ b1,
    const float* __restrict__ W2,
    const float* __restrict__ b2,
    const int* __restrict__ nbr,
    const int* __restrict__ cntbuf,
    const float* __restrict__ centers,
    float* __restrict__ out)
{
    __shared__ float WT[64 * 68];
    __shared__ float featL[4][32 * 68];

    const int tid = threadIdx.x, wave = tid >> 6, lane = tid & 63;
    const int c = blockIdx.x * 4 + wave;
    const int b = c >> 11;
    const int cnt = cntbuf[c];

    for (int idx = tid; idx < 67 * 64; idx += 256) {
        const int i = idx >> 6, h = idx & 63;
        WT[h * 68 + i] = W1[idx];
    }
    if (tid < 64) WT[tid * 68 + 67] = 0.0f;

    const float ctr0 = centers[c * 3 + 0];
    const float ctr1 = centers[c * 3 + 1];
    const float ctr2 = centers[c * 3 + 2];
    for (int k = 0; k < cnt; ++k) {
        const int j = nbr[c * KK + k];
        featL[wave][k * 68 + lane] = x[((size_t)b * NN + j) * FF + lane];
        if (lane < 3) {
            const float pj = pos[((size_t)b * NN + j) * 3 + lane];
            const float ci = (lane == 0) ? ctr0 : ((lane == 1) ? ctr1 : ctr2);
            featL[wave][k * 68 + 64 + lane] = __fsub_rn(pj, ci);
        }
        if (lane == 3) featL[wave][k * 68 + 67] = 0.0f;
    }
    __syncthreads();

    float wreg[68];
#pragma unroll
    for (int i4 = 0; i4 < 17; ++i4) {
        const float4 v = *(const float4*)&WT[lane * 68 + i4 * 4];
        wreg[i4 * 4 + 0] = v.x; wreg[i4 * 4 + 1] = v.y;
        wreg[i4 * 4 + 2] = v.z; wreg[i4 * 4 + 3] = v.w;
    }
    const float bias1 = b1[lane];
    for (int k = 0; k < cnt; ++k) {
        float acc = bias1;
#pragma unroll
        for (int i4 = 0; i4 < 17; ++i4) {
            const float4 f = *(const float4*)&featL[wave][k * 68 + i4 * 4];
            acc = fmaf(f.x, wreg[i4 * 4 + 0], acc);
            acc = fmaf(f.y, wreg[i4 * 4 + 1], acc);
            acc = fmaf(f.z, wreg[i4 * 4 + 2], acc);
            acc = fmaf(f.w, wreg[i4 * 4 + 3], acc);
        }
        featL[wave][k * 68 + lane] = fmaxf(acc, 0.0f);
    }
    __syncthreads();

    for (int idx = tid; idx < 64 * 64; idx += 256) {
        const int i = idx >> 6, h = idx & 63;
        WT[h * 68 + i] = W2[idx];
    }
    __syncthreads();

#pragma unroll
    for (int i4 = 0; i4 < 16; ++i4) {
        const float4 v = *(const float4*)&WT[lane * 68 + i4 * 4];
        wreg[i4 * 4 + 0] = v.x; wreg[i4 * 4 + 1] = v.y;
        wreg[i4 * 4 + 2] = v.z; wreg[i4 * 4 + 3] = v.w;
    }
    const float bias2 = b2[lane];
    float m = -INFINITY;
    for (int k = 0; k < cnt; ++k) {
        float acc = bias2;
#pragma unroll
        for (int i4 = 0; i4 < 16; ++i4) {
            const float4 f = *(const float4*)&featL[wave][k * 68 + i4 * 4];
            acc = fmaf(f.x, wreg[i4 * 4 + 0], acc);
            acc = fmaf(f.y, wreg[i4 * 4 + 1], acc);
            acc = fmaf(f.z, wreg[i4 * 4 + 2], acc);
            acc = fmaf(f.w, wreg[i4 * 4 + 3], acc);
        }
        m = fmaxf(m, fmaxf(acc, 0.0f));
    }
    out[(size_t)c * HH + lane] = (cnt > 0) ? m : 0.0f;
}

extern "C" void kernel_launch(void* const* d_in, const int* in_sizes, int n_in,
                              void* d_out, int out_size, void* d_ws, size_t ws_size,
                              hipStream_t stream) {
    const float* x   = (const float*)d_in[0];
    const float* pos = (const float*)d_in[1];
    const float* W1  = (const float*)d_in[3];
    const float* b1  = (const float*)d_in[4];
    const float* W2  = (const float*)d_in[5];
    const float* b2  = (const float*)d_in[6];

    float* out         = (float*)d_out;
    float* centers_out = out + (size_t)NB * MM * HH;
    float* batch_out   = centers_out + (size_t)NB * MM * 3;

    char* ws = (char*)d_ws;
    int* samp   = (int*)ws;
    int* cntbuf = (int*)(ws + (size_t)NB * MM * 4);
    int* nbr    = (int*)(ws + (size_t)2 * NB * MM * 4);

    fps_kernel<<<NB, FT, 0, stream>>>(pos, samp, centers_out, batch_out);
    knn_kernel<<<(NB * MM) / 4, 256, 0, stream>>>(pos, samp, nbr, cntbuf);
    mlp_kernel<<<(NB * MM) / 4, 256, 0, stream>>>(x, pos, W1, b1, W2, b2,
                                                  nbr, cntbuf, centers_out, out);
}